// Round 7
// baseline (789.726 us; speedup 1.0000x reference)
//
#include <hip/hip_runtime.h>
#include <hip/hip_bf16.h>

#define NN 50000
#define HD 128
#define NL 4
#define BN_EPS 1e-5f

typedef __attribute__((ext_vector_type(8))) short short8;
typedef __attribute__((ext_vector_type(4))) float f32x4;

__device__ inline ushort f2bf(float f){
  uint u = __float_as_uint(f);
  uint r = (u + 0x7fffu + ((u >> 16) & 1u)) >> 16;
  return (ushort)r;
}
__device__ inline float bflo(uint u){ return __uint_as_float(u << 16); }
__device__ inline float bfhi(uint u){ return __uint_as_float(u & 0xffff0000u); }

// ---------------- cast fp32 -> bf16 ----------------
__global__ void cast_f32_bf16x4(const float* __restrict__ in, ushort* __restrict__ out, int n4){
  int i = blockIdx.x * blockDim.x + threadIdx.x;
  int stride = gridDim.x * blockDim.x;
  const float4* in4 = (const float4*)in;
  for (; i < n4; i += stride){
    float4 v = in4[i];
    ushort4 r;
    r.x = f2bf(v.x); r.y = f2bf(v.y); r.z = f2bf(v.z); r.w = f2bf(v.w);
    *(ushort4*)(out + i * 4) = r;
  }
}

__global__ void cast_weights(const float* __restrict__ w1, const float* __restrict__ w2,
                             const float* __restrict__ wf, ushort* __restrict__ wb){
  int i = blockIdx.x * 256 + threadIdx.x;
  if (i >= 36864) return;
  const float* src;
  if (i < 16384)      src = w1 + i * 4;
  else if (i < 32768) src = w2 + (i - 16384) * 4;
  else                src = wf + (i - 32768) * 4;
  float4 v = *(const float4*)src;
  ushort4 r;
  r.x = f2bf(v.x); r.y = f2bf(v.y); r.z = f2bf(v.z); r.w = f2bf(v.w);
  *(ushort4*)(wb + i * 4) = r;
}

// ---------------- CSR build: fill1 (hist+slot, 4 edges/thread MLP), scan, fill2 ----------------
__global__ void fill1_kernel(const int* __restrict__ dst, int* __restrict__ cnt,
                             int* __restrict__ pos, int E){
  int e = (blockIdx.x * 256 + threadIdx.x) * 4;
  if (e + 4 <= E){
    int4 d = *(const int4*)(dst + e);
    int4 p;
    p.x = atomicAdd(&cnt[d.x], 1);
    p.y = atomicAdd(&cnt[d.y], 1);
    p.z = atomicAdd(&cnt[d.z], 1);
    p.w = atomicAdd(&cnt[d.w], 1);
    *(int4*)(pos + e) = p;
  } else {
    for (; e < E; ++e) pos[e] = atomicAdd(&cnt[dst[e]], 1);
  }
}

__global__ void scan1_kernel(const int* __restrict__ deg, int* __restrict__ incl,
                             int* __restrict__ bsum, int n){
  __shared__ int tmp[1024];
  int gid = blockIdx.x * 1024 + threadIdx.x;
  int v = (gid < n) ? deg[gid] : 0;
  tmp[threadIdx.x] = v;
  __syncthreads();
  for (int ofs = 1; ofs < 1024; ofs <<= 1){
    int t = tmp[threadIdx.x];
    int a = (threadIdx.x >= ofs) ? tmp[threadIdx.x - ofs] : 0;
    __syncthreads();
    tmp[threadIdx.x] = t + a;
    __syncthreads();
  }
  if (gid < n) incl[gid] = tmp[threadIdx.x];
  if (threadIdx.x == 1023) bsum[blockIdx.x] = tmp[1023];
}

__global__ void scan2_kernel(const int* __restrict__ bsum, int* __restrict__ base,
                             int* __restrict__ off, int nb, int n){
  if (threadIdx.x == 0){
    int run = 0;
    for (int i = 0; i < nb; ++i){ base[i] = run; run += bsum[i]; }
    off[n] = run;
  }
}

__global__ void scan3_kernel(const int* __restrict__ deg, const int* __restrict__ incl,
                             const int* __restrict__ base, int* __restrict__ off, int n){
  int gid = blockIdx.x * 1024 + threadIdx.x;
  if (gid < n) off[gid] = incl[gid] - deg[gid] + base[blockIdx.x];
}

__global__ void fill2_kernel(const int* __restrict__ src, const int* __restrict__ dst,
                             const int* __restrict__ off, const int* __restrict__ pos,
                             int* __restrict__ csrc, int E){
  int e = (blockIdx.x * 256 + threadIdx.x) * 4;
  if (e + 4 <= E){
    int4 d = *(const int4*)(dst + e);
    int4 p = *(const int4*)(pos + e);
    int4 s = *(const int4*)(src + e);
    csrc[off[d.x] + p.x] = s.x;
    csrc[off[d.y] + p.y] = s.y;
    csrc[off[d.z] + p.z] = s.z;
    csrc[off[d.w] + p.w] = s.w;
  } else {
    for (; e < E; ++e) csrc[off[dst[e]] + pos[e]] = src[e];
  }
}

// ---------------- aggregation: one wave per node ----------------
__global__ __launch_bounds__(256) void agg_kernel(const ushort* __restrict__ xb,
                                                  const int* __restrict__ off,
                                                  const int* __restrict__ csrc,
                                                  ushort* __restrict__ h){
  int node = blockIdx.x * 4 + (threadIdx.x >> 6);
  int lane = threadIdx.x & 63;
  const uint* xr = (const uint*)xb;
  uint self = xr[node * 64 + lane];
  float ax = bflo(self), ay = bfhi(self);
  int s = off[node], e = off[node + 1];
  int j = s;
  for (; j + 8 <= e; j += 8){
    uint v0 = xr[csrc[j+0]*64+lane], v1 = xr[csrc[j+1]*64+lane];
    uint v2 = xr[csrc[j+2]*64+lane], v3 = xr[csrc[j+3]*64+lane];
    uint v4 = xr[csrc[j+4]*64+lane], v5 = xr[csrc[j+5]*64+lane];
    uint v6 = xr[csrc[j+6]*64+lane], v7 = xr[csrc[j+7]*64+lane];
    ax += bflo(v0)+bflo(v1)+bflo(v2)+bflo(v3)+bflo(v4)+bflo(v5)+bflo(v6)+bflo(v7);
    ay += bfhi(v0)+bfhi(v1)+bfhi(v2)+bfhi(v3)+bfhi(v4)+bfhi(v5)+bfhi(v6)+bfhi(v7);
  }
  for (; j + 4 <= e; j += 4){
    uint v0 = xr[csrc[j+0]*64+lane], v1 = xr[csrc[j+1]*64+lane];
    uint v2 = xr[csrc[j+2]*64+lane], v3 = xr[csrc[j+3]*64+lane];
    ax += bflo(v0)+bflo(v1)+bflo(v2)+bflo(v3);
    ay += bfhi(v0)+bfhi(v1)+bfhi(v2)+bfhi(v3);
  }
  for (; j < e; ++j){
    uint v = xr[csrc[j] * 64 + lane];
    ax += bflo(v); ay += bfhi(v);
  }
  uint o = (uint)f2bf(ax) | ((uint)f2bf(ay) << 16);
  ((uint*)h)[node * 64 + lane] = o;
}

// ---------------- partial reduce -> BN affine params (1 block) ----------------
__global__ void reduce_kernel(const float* __restrict__ P, int nrows,
                              const float* __restrict__ gA, const float* __restrict__ gB,
                              const float* __restrict__ bB, int mode,
                              float* __restrict__ params){
  __shared__ float sbuf[256];
  int c = threadIdx.x;
  float a0 = 0.f, a1 = 0.f, a2 = 0.f, a3 = 0.f;
  int b = 0;
  for (; b + 4 <= nrows; b += 4){
    a0 += P[(b+0)*256 + c]; a1 += P[(b+1)*256 + c];
    a2 += P[(b+2)*256 + c]; a3 += P[(b+3)*256 + c];
  }
  for (; b < nrows; ++b) a0 += P[b*256 + c];
  sbuf[c] = (a0 + a1) + (a2 + a3);
  __syncthreads();
  if (c < 128){
    const float invN = 1.f / (float)NN;
    float mu = sbuf[c] * invN;
    float var = fmaxf(sbuf[128 + c] * invN - mu * mu, 0.f);
    float S, T;
    if (mode == 0){
      S = gA[c] * rsqrtf(var + BN_EPS);
      T = gB[c] - mu * S;
    } else {
      float inv2 = rsqrtf(var + BN_EPS);
      float tt = gA[c] * inv2;
      float inv3 = rsqrtf(tt * tt * var + BN_EPS);
      S = tt * inv3 * gB[c];
      T = bB[c] - mu * S;
    }
    params[c] = S;
    params[128 + c] = T;
  }
}

// ---------------- GEMM (A bf16): Y = A @ W^T + bias; per-block partial stats row ----------------
__global__ __launch_bounds__(256) void gemm_kernel(const ushort* __restrict__ A,
                                                   const ushort* __restrict__ W,
                                                   const float* __restrict__ bias,
                                                   float* __restrict__ Y,
                                                   float* __restrict__ P,
                                                   int nTiles){
  __shared__ uint4 w4[128 * 17];
  __shared__ float ssum[128];
  __shared__ float ssq[128];
  const uint4* Wg = (const uint4*)W;
  for (int c = threadIdx.x; c < 2048; c += 256){
    w4[(c >> 4) * 17 + (c & 15)] = Wg[c];
  }
  if (threadIdx.x < 128){ ssum[threadIdx.x] = 0.f; ssq[threadIdx.x] = 0.f; }
  __syncthreads();

  int wave = threadIdx.x >> 6;
  int lane = threadIdx.x & 63;
  int m = lane & 15, q = lane >> 4;
  int t0 = blockIdx.x * 8 + wave * 2;
  int t1 = t0 + 1;
  bool v0 = t0 < nTiles, v1 = t1 < nTiles;
  const uint4* A4 = (const uint4*)A;

  f32x4 acc0[8], acc1[8];
#pragma unroll
  for (int i = 0; i < 8; ++i){ acc0[i] = (f32x4)0.f; acc1[i] = (f32x4)0.f; }

#pragma unroll
  for (int kt = 0; kt < 4; ++kt){
    short8 a0 = (short8)0, a1 = (short8)0;
    if (v0){ uint4 t = A4[(t0 * 16 + m) * 16 + kt * 4 + q]; a0 = *(short8*)&t; }
    if (v1){ uint4 t = A4[(t1 * 16 + m) * 16 + kt * 4 + q]; a1 = *(short8*)&t; }
#pragma unroll
    for (int to = 0; to < 8; ++to){
      uint4 bw = w4[(to * 16 + m) * 17 + kt * 4 + q];
      short8 bb = *(short8*)&bw;
      acc0[to] = __builtin_amdgcn_mfma_f32_16x16x32_bf16(a0, bb, acc0[to], 0, 0, 0);
      acc1[to] = __builtin_amdgcn_mfma_f32_16x16x32_bf16(a1, bb, acc1[to], 0, 0, 0);
    }
  }

#pragma unroll
  for (int to = 0; to < 8; ++to){
    int col = to * 16 + m;
    float bc = bias[col];
    if (v0){
      float ls = 0.f, lq = 0.f;
#pragma unroll
      for (int r = 0; r < 4; ++r){
        float v = acc0[to][r] + bc;
        Y[(t0 * 16 + q * 4 + r) * 128 + col] = v;
        ls += v; lq += v * v;
      }
      atomicAdd(&ssum[col], ls); atomicAdd(&ssq[col], lq);
    }
    if (v1){
      float ls = 0.f, lq = 0.f;
#pragma unroll
      for (int r = 0; r < 4; ++r){
        float v = acc1[to][r] + bc;
        Y[(t1 * 16 + q * 4 + r) * 128 + col] = v;
        ls += v; lq += v * v;
      }
      atomicAdd(&ssum[col], ls); atomicAdd(&ssq[col], lq);
    }
  }
  __syncthreads();
  P[blockIdx.x * 256 + threadIdx.x] =
      (threadIdx.x < 128) ? ssum[threadIdx.x] : ssq[threadIdx.x - 128];
}

// ---------------- GEMM with BN-on-load: Y = relu(A*s+t)bf16 @ W^T + bias ----------------
__global__ __launch_bounds__(256) void gemm_fused(const float* A,
                                                  const ushort* __restrict__ W,
                                                  const float* __restrict__ bias,
                                                  float* Y,
                                                  float* __restrict__ P,
                                                  const float* __restrict__ params,
                                                  int nTiles){
  __shared__ uint4 w4[128 * 17];
  __shared__ float ssum[128];
  __shared__ float ssq[128];
  __shared__ __align__(16) float sS[128];
  __shared__ __align__(16) float sT[128];
  const uint4* Wg = (const uint4*)W;
  for (int c = threadIdx.x; c < 2048; c += 256){
    w4[(c >> 4) * 17 + (c & 15)] = Wg[c];
  }
  if (threadIdx.x < 128){
    sS[threadIdx.x] = params[threadIdx.x];
    sT[threadIdx.x] = params[128 + threadIdx.x];
    ssum[threadIdx.x] = 0.f; ssq[threadIdx.x] = 0.f;
  }
  __syncthreads();

  int wave = threadIdx.x >> 6;
  int lane = threadIdx.x & 63;
  int m = lane & 15, q = lane >> 4;
  int t0 = blockIdx.x * 8 + wave * 2;
  int t1 = t0 + 1;
  bool v0 = t0 < nTiles, v1 = t1 < nTiles;

  f32x4 acc0[8], acc1[8];
#pragma unroll
  for (int i = 0; i < 8; ++i){ acc0[i] = (f32x4)0.f; acc1[i] = (f32x4)0.f; }

#pragma unroll
  for (int kt = 0; kt < 4; ++kt){
    int kc = kt * 32 + q * 8;
    float4 s0 = *(const float4*)&sS[kc], s1 = *(const float4*)&sS[kc + 4];
    float4 tt0 = *(const float4*)&sT[kc], tt1 = *(const float4*)&sT[kc + 4];
    short8 a0 = (short8)0, a1 = (short8)0;
    if (v0){
      const float4* p = (const float4*)(A + (t0 * 16 + m) * 128 + kc);
      float4 u = p[0], v = p[1];
      uint4 pk;
      pk.x = (uint)f2bf(fmaxf(u.x*s0.x+tt0.x,0.f)) | ((uint)f2bf(fmaxf(u.y*s0.y+tt0.y,0.f)) << 16);
      pk.y = (uint)f2bf(fmaxf(u.z*s0.z+tt0.z,0.f)) | ((uint)f2bf(fmaxf(u.w*s0.w+tt0.w,0.f)) << 16);
      pk.z = (uint)f2bf(fmaxf(v.x*s1.x+tt1.x,0.f)) | ((uint)f2bf(fmaxf(v.y*s1.y+tt1.y,0.f)) << 16);
      pk.w = (uint)f2bf(fmaxf(v.z*s1.z+tt1.z,0.f)) | ((uint)f2bf(fmaxf(v.w*s1.w+tt1.w,0.f)) << 16);
      a0 = *(short8*)&pk;
    }
    if (v1){
      const float4* p = (const float4*)(A + (t1 * 16 + m) * 128 + kc);
      float4 u = p[0], v = p[1];
      uint4 pk;
      pk.x = (uint)f2bf(fmaxf(u.x*s0.x+tt0.x,0.f)) | ((uint)f2bf(fmaxf(u.y*s0.y+tt0.y,0.f)) << 16);
      pk.y = (uint)f2bf(fmaxf(u.z*s0.z+tt0.z,0.f)) | ((uint)f2bf(fmaxf(u.w*s0.w+tt0.w,0.f)) << 16);
      pk.z = (uint)f2bf(fmaxf(v.x*s1.x+tt1.x,0.f)) | ((uint)f2bf(fmaxf(v.y*s1.y+tt1.y,0.f)) << 16);
      pk.w = (uint)f2bf(fmaxf(v.z*s1.z+tt1.z,0.f)) | ((uint)f2bf(fmaxf(v.w*s1.w+tt1.w,0.f)) << 16);
      a1 = *(short8*)&pk;
    }
#pragma unroll
    for (int to = 0; to < 8; ++to){
      uint4 bw = w4[(to * 16 + m) * 17 + kt * 4 + q];
      short8 bb = *(short8*)&bw;
      acc0[to] = __builtin_amdgcn_mfma_f32_16x16x32_bf16(a0, bb, acc0[to], 0, 0, 0);
      acc1[to] = __builtin_amdgcn_mfma_f32_16x16x32_bf16(a1, bb, acc1[to], 0, 0, 0);
    }
  }

  bool dost = (P != nullptr);
#pragma unroll
  for (int to = 0; to < 8; ++to){
    int col = to * 16 + m;
    float bc = bias[col];
    if (v0){
      float ls = 0.f, lq = 0.f;
#pragma unroll
      for (int r = 0; r < 4; ++r){
        float v = acc0[to][r] + bc;
        Y[(t0 * 16 + q * 4 + r) * 128 + col] = v;
        ls += v; lq += v * v;
      }
      if (dost){ atomicAdd(&ssum[col], ls); atomicAdd(&ssq[col], lq); }
    }
    if (v1){
      float ls = 0.f, lq = 0.f;
#pragma unroll
      for (int r = 0; r < 4; ++r){
        float v = acc1[to][r] + bc;
        Y[(t1 * 16 + q * 4 + r) * 128 + col] = v;
        ls += v; lq += v * v;
      }
      if (dost){ atomicAdd(&ssum[col], ls); atomicAdd(&ssq[col], lq); }
    }
  }
  __syncthreads();
  if (dost){
    P[blockIdx.x * 256 + threadIdx.x] =
        (threadIdx.x < 128) ? ssum[threadIdx.x] : ssq[threadIdx.x - 128];
  }
}

// ---------------- transform: relu(y*S+T) -> bf16, params precomputed ----------------
__global__ __launch_bounds__(256) void transform_kernel(const float* __restrict__ y,
                                                        const float* __restrict__ params,
                                                        ushort* __restrict__ ob){
  __shared__ __align__(16) float sS[128];
  __shared__ __align__(16) float sT[128];
  if (threadIdx.x < 128){
    sS[threadIdx.x] = params[threadIdx.x];
    sT[threadIdx.x] = params[128 + threadIdx.x];
  }
  __syncthreads();
  const int n4 = NN * HD / 4;
  int i = blockIdx.x * 256 + threadIdx.x;
  int stride = gridDim.x * 256;
  const float4* y4 = (const float4*)y;
  for (; i < n4; i += stride){
    int col = (i * 4) & 127;
    float4 v = y4[i];
    float4 s = *(const float4*)&sS[col];
    float4 t = *(const float4*)&sT[col];
    ushort4 r;
    r.x = f2bf(fmaxf(v.x * s.x + t.x, 0.f));
    r.y = f2bf(fmaxf(v.y * s.y + t.y, 0.f));
    r.z = f2bf(fmaxf(v.z * s.z + t.z, 0.f));
    r.w = f2bf(fmaxf(v.w * s.w + t.w, 0.f));
    *(ushort4*)(ob + i * 4) = r;
  }
}

extern "C" void kernel_launch(void* const* d_in, const int* in_sizes, int n_in,
                              void* d_out, int out_size, void* d_ws, size_t ws_size,
                              hipStream_t stream) {
  const float* x     = (const float*)d_in[0];
  const int*   ei    = (const int*)d_in[1];
  const float* fc1_w = (const float*)d_in[2];
  const float* fc1_b = (const float*)d_in[3];
  const float* bn1_g = (const float*)d_in[4];
  const float* bn1_b = (const float*)d_in[5];
  const float* fc2_w = (const float*)d_in[6];
  const float* fc2_b = (const float*)d_in[7];
  const float* bn2_g = (const float*)d_in[8];
  const float* bn3_g = (const float*)d_in[10];
  const float* bn3_b = (const float*)d_in[11];
  const float* fc_w  = (const float*)d_in[12];
  const float* fc_b  = (const float*)d_in[13];

  int E = in_sizes[1] / 2;
  const int* srcp = ei;
  const int* dstp = ei + E;

  char* ws = (char*)d_ws;
  int*    off    = (int*)(ws + 0);           // (N+1) ints
  int*    cnt    = (int*)(ws + 200064);      // N ints
  int*    pos    = (int*)(ws + 400128);      // E ints
  int*    csrc   = (int*)(ws + 3600128);     // E ints (aliased as `incl` pre-fill2)
  ushort* wb     = (ushort*)(ws + 6800128);  // 147456 bf16
  float*  params = (float*)(ws + 7095040);   // 256 floats (S|T)
  int*    sscr   = (int*)(ws + 7096064);     // scan bsum/base
  float*  P      = (float*)(ws + 7097088);   // 391 x 256 partials
  ushort* xb     = (ushort*)(ws + 7497472);  // N*128 bf16
  ushort* hb     = (ushort*)(ws + 20297472); // N*128 bf16
  float*  y      = (float*)(ws + 33097472);  // N*128 f32

  int* incl = csrc;
  int* bsum = sscr;
  int* base = sscr + 64;

  hipMemsetAsync(cnt, 0, 200064, stream);

  cast_f32_bf16x4<<<2048, 256, 0, stream>>>(x, xb, NN * HD / 4);
  cast_weights<<<144, 256, 0, stream>>>(fc1_w, fc2_w, fc_w, wb);

  const int EB4 = (E / 4 + 255) / 256 + 1;
  const int SB = (NN + 1023) / 1024;
  fill1_kernel<<<EB4, 256, 0, stream>>>(dstp, cnt, pos, E);
  scan1_kernel<<<SB, 1024, 0, stream>>>(cnt, incl, bsum, NN);
  scan2_kernel<<<1, 64, 0, stream>>>(bsum, base, off, SB, NN);
  scan3_kernel<<<SB, 1024, 0, stream>>>(cnt, incl, base, off, NN);
  fill2_kernel<<<EB4, 256, 0, stream>>>(srcp, dstp, off, pos, csrc, E);

  const int nT = NN / 16;         // 3125 row tiles
  const int gb = (nT + 7) / 8;    // 391 blocks

  for (int i = 0; i < NL; ++i){
    agg_kernel<<<NN / 4, 256, 0, stream>>>(xb, off, csrc, hb);
    gemm_kernel<<<gb, 256, 0, stream>>>(hb, wb + i * 16384, fc1_b + i * 128,
                                        y, P, nT);
    reduce_kernel<<<1, 256, 0, stream>>>(P, gb, bn1_g + i * 128, bn1_b + i * 128,
                                         bn1_b + i * 128, 0, params);
    gemm_fused<<<gb, 256, 0, stream>>>(y, wb + 65536 + i * 16384, fc2_b + i * 128,
                                       y, P, params, nT);
    reduce_kernel<<<1, 256, 0, stream>>>(P, gb, bn2_g + i * 128, bn3_g + i * 128,
                                         bn3_b + i * 128, 1, params);
    if (i < NL - 1){
      transform_kernel<<<2048, 256, 0, stream>>>(y, params, xb);
    }
  }

  // classifier: A = relu(bn3(bn2(y_last))) applied on load; no stats
  gemm_fused<<<gb, 256, 0, stream>>>(y, wb + 131072, fc_b, (float*)d_out,
                                     nullptr, params, nT);
}

// Round 8
// 486.258 us; speedup vs baseline: 1.6241x; 1.6241x over previous
//
#include <hip/hip_runtime.h>
#include <hip/hip_bf16.h>

#define NN 50000
#define HD 128
#define NL 4
#define BN_EPS 1e-5f
#define NTILES 3125

typedef __attribute__((ext_vector_type(8))) short short8;
typedef __attribute__((ext_vector_type(4))) float f32x4;

__device__ inline ushort f2bf(float f){
  uint u = __float_as_uint(f);
  uint r = (u + 0x7fffu + ((u >> 16) & 1u)) >> 16;
  return (ushort)r;
}
__device__ inline float bflo(uint u){ return __uint_as_float(u << 16); }
__device__ inline float bfhi(uint u){ return __uint_as_float(u & 0xffff0000u); }

// ---------------- cast fp32 -> bf16 ----------------
__global__ void cast_f32_bf16x4(const float* __restrict__ in, ushort* __restrict__ out, int n4){
  int i = blockIdx.x * blockDim.x + threadIdx.x;
  int stride = gridDim.x * blockDim.x;
  const float4* in4 = (const float4*)in;
  for (; i < n4; i += stride){
    float4 v = in4[i];
    ushort4 r;
    r.x = f2bf(v.x); r.y = f2bf(v.y); r.z = f2bf(v.z); r.w = f2bf(v.w);
    *(ushort4*)(out + i * 4) = r;
  }
}

__global__ void cast_weights(const float* __restrict__ w1, const float* __restrict__ w2,
                             const float* __restrict__ wf, ushort* __restrict__ wb){
  int i = blockIdx.x * 256 + threadIdx.x;
  if (i >= 36864) return;
  const float* src;
  if (i < 16384)      src = w1 + i * 4;
  else if (i < 32768) src = w2 + (i - 16384) * 4;
  else                src = wf + (i - 32768) * 4;
  float4 v = *(const float4*)src;
  ushort4 r;
  r.x = f2bf(v.x); r.y = f2bf(v.y); r.z = f2bf(v.z); r.w = f2bf(v.w);
  *(ushort4*)(wb + i * 4) = r;
}

// ---------------- CSR build ----------------
__global__ void fill1_kernel(const int* __restrict__ dst, int* __restrict__ cnt,
                             int* __restrict__ pos, int E){
  int e = (blockIdx.x * 256 + threadIdx.x) * 4;
  if (e + 4 <= E){
    int4 d = *(const int4*)(dst + e);
    int4 p;
    p.x = atomicAdd(&cnt[d.x], 1);
    p.y = atomicAdd(&cnt[d.y], 1);
    p.z = atomicAdd(&cnt[d.z], 1);
    p.w = atomicAdd(&cnt[d.w], 1);
    *(int4*)(pos + e) = p;
  } else {
    for (; e < E; ++e) pos[e] = atomicAdd(&cnt[dst[e]], 1);
  }
}

__global__ void scan1_kernel(const int* __restrict__ deg, int* __restrict__ incl,
                             int* __restrict__ bsum, int n){
  __shared__ int tmp[1024];
  int gid = blockIdx.x * 1024 + threadIdx.x;
  int v = (gid < n) ? deg[gid] : 0;
  tmp[threadIdx.x] = v;
  __syncthreads();
  for (int ofs = 1; ofs < 1024; ofs <<= 1){
    int t = tmp[threadIdx.x];
    int a = (threadIdx.x >= ofs) ? tmp[threadIdx.x - ofs] : 0;
    __syncthreads();
    tmp[threadIdx.x] = t + a;
    __syncthreads();
  }
  if (gid < n) incl[gid] = tmp[threadIdx.x];
  if (threadIdx.x == 1023) bsum[blockIdx.x] = tmp[1023];
}

__global__ void scan2_kernel(const int* __restrict__ bsum, int* __restrict__ base,
                             int* __restrict__ off, int nb, int n){
  if (threadIdx.x == 0){
    int run = 0;
    for (int i = 0; i < nb; ++i){ base[i] = run; run += bsum[i]; }
    off[n] = run;
  }
}

__global__ void scan3_kernel(const int* __restrict__ deg, const int* __restrict__ incl,
                             const int* __restrict__ base, int* __restrict__ off, int n){
  int gid = blockIdx.x * 1024 + threadIdx.x;
  if (gid < n) off[gid] = incl[gid] - deg[gid] + base[blockIdx.x];
}

__global__ void fill2_kernel(const int* __restrict__ src, const int* __restrict__ dst,
                             const int* __restrict__ off, const int* __restrict__ pos,
                             int* __restrict__ csrc, int E){
  int e = (blockIdx.x * 256 + threadIdx.x) * 4;
  if (e + 4 <= E){
    int4 d = *(const int4*)(dst + e);
    int4 p = *(const int4*)(pos + e);
    int4 s = *(const int4*)(src + e);
    csrc[off[d.x] + p.x] = s.x;
    csrc[off[d.y] + p.y] = s.y;
    csrc[off[d.z] + p.z] = s.z;
    csrc[off[d.w] + p.w] = s.w;
  } else {
    for (; e < E; ++e) csrc[off[dst[e]] + pos[e]] = src[e];
  }
}

// ---------------- BN param computation (device helper, threads<128) ----------------
__device__ inline void bn_params_tid(const float* st, const float* gA, const float* gB,
                                     const float* bB, int mode, float* sS, float* sT){
  int c = threadIdx.x;
  if (c < 128){
    const float invN = 1.f / (float)NN;
    float mu = st[c] * invN;
    float var = fmaxf(st[128 + c] * invN - mu * mu, 0.f);
    float S, T;
    if (mode == 0){
      S = gA[c] * rsqrtf(var + BN_EPS);
      T = gB[c] - mu * S;
    } else {
      float inv2 = rsqrtf(var + BN_EPS);
      float tt = gA[c] * inv2;
      float inv3 = rsqrtf(tt * tt * var + BN_EPS);
      S = tt * inv3 * gB[c];
      T = bB[c] - mu * S;
    }
    sS[c] = S; sT[c] = T;
  }
}

// ---------------- aggregation, layer 0: h = x + sum(neigh) ----------------
__global__ __launch_bounds__(256) void agg_kernel(const ushort* __restrict__ xb,
                                                  const int* __restrict__ off,
                                                  const int* __restrict__ csrc,
                                                  ushort* __restrict__ h){
  int node = blockIdx.x * 4 + (threadIdx.x >> 6);
  int lane = threadIdx.x & 63;
  const uint* xr = (const uint*)xb;
  uint self = xr[node * 64 + lane];
  float ax = bflo(self), ay = bfhi(self);
  int s = off[node], e = off[node + 1];
  int j = s;
  for (; j + 8 <= e; j += 8){
    uint v0 = xr[csrc[j+0]*64+lane], v1 = xr[csrc[j+1]*64+lane];
    uint v2 = xr[csrc[j+2]*64+lane], v3 = xr[csrc[j+3]*64+lane];
    uint v4 = xr[csrc[j+4]*64+lane], v5 = xr[csrc[j+5]*64+lane];
    uint v6 = xr[csrc[j+6]*64+lane], v7 = xr[csrc[j+7]*64+lane];
    ax += bflo(v0)+bflo(v1)+bflo(v2)+bflo(v3)+bflo(v4)+bflo(v5)+bflo(v6)+bflo(v7);
    ay += bfhi(v0)+bfhi(v1)+bfhi(v2)+bfhi(v3)+bfhi(v4)+bfhi(v5)+bfhi(v6)+bfhi(v7);
  }
  for (; j + 4 <= e; j += 4){
    uint v0 = xr[csrc[j+0]*64+lane], v1 = xr[csrc[j+1]*64+lane];
    uint v2 = xr[csrc[j+2]*64+lane], v3 = xr[csrc[j+3]*64+lane];
    ax += bflo(v0)+bflo(v1)+bflo(v2)+bflo(v3);
    ay += bfhi(v0)+bfhi(v1)+bfhi(v2)+bfhi(v3);
  }
  for (; j < e; ++j){
    uint v = xr[csrc[j] * 64 + lane];
    ax += bflo(v); ay += bfhi(v);
  }
  uint o = (uint)f2bf(ax) | ((uint)f2bf(ay) << 16);
  ((uint*)h)[node * 64 + lane] = o;
}

// ---------------- aggregation, layers 1..3: gather y2, apply bn23 affine+relu on the fly ----------------
__global__ __launch_bounds__(256) void agg_bn_kernel(const ushort* __restrict__ yb,
                                                     const int* __restrict__ off,
                                                     const int* __restrict__ csrc,
                                                     const float* __restrict__ statsIn,
                                                     const float* __restrict__ g2,
                                                     const float* __restrict__ g3,
                                                     const float* __restrict__ b3,
                                                     ushort* __restrict__ h){
  __shared__ float sS[128];
  __shared__ float sT[128];
  bn_params_tid(statsIn, g2, g3, b3, 1, sS, sT);
  __syncthreads();
  int node = blockIdx.x * 4 + (threadIdx.x >> 6);
  int lane = threadIdx.x & 63;
  float S0 = sS[lane*2], T0 = sT[lane*2];
  float S1 = sS[lane*2+1], T1 = sT[lane*2+1];
  const uint* xr = (const uint*)yb;
  uint self = xr[node * 64 + lane];
  float ax = fmaxf(bflo(self)*S0+T0, 0.f), ay = fmaxf(bfhi(self)*S1+T1, 0.f);
  int s = off[node], e = off[node + 1];
  int j = s;
  for (; j + 4 <= e; j += 4){
    uint v0 = xr[csrc[j+0]*64+lane], v1 = xr[csrc[j+1]*64+lane];
    uint v2 = xr[csrc[j+2]*64+lane], v3 = xr[csrc[j+3]*64+lane];
    ax += fmaxf(bflo(v0)*S0+T0,0.f) + fmaxf(bflo(v1)*S0+T0,0.f)
        + fmaxf(bflo(v2)*S0+T0,0.f) + fmaxf(bflo(v3)*S0+T0,0.f);
    ay += fmaxf(bfhi(v0)*S1+T1,0.f) + fmaxf(bfhi(v1)*S1+T1,0.f)
        + fmaxf(bfhi(v2)*S1+T1,0.f) + fmaxf(bfhi(v3)*S1+T1,0.f);
  }
  for (; j < e; ++j){
    uint v = xr[csrc[j] * 64 + lane];
    ax += fmaxf(bflo(v)*S0+T0,0.f);
    ay += fmaxf(bfhi(v)*S1+T1,0.f);
  }
  uint o = (uint)f2bf(ax) | ((uint)f2bf(ay) << 16);
  ((uint*)h)[node * 64 + lane] = o;
}

// ---------------- unified GEMM: Y = [relu(affine(A))] @ W^T + bias ----------------
// 512 threads, 8 waves, 1 tile (16 rows) per wave; grid 391.
// A bf16 [N,128]. If statsIn: affine+relu applied to A on load (params from stats, inline).
// Output: Yb (bf16) or Yf (f32). Optional statsOut: column sum/sumsq via LDS + global atomics.
__global__ __launch_bounds__(512) void gemm_kernel(const ushort* __restrict__ A,
                                                   const ushort* __restrict__ W,
                                                   const float* __restrict__ bias,
                                                   ushort* __restrict__ Yb,
                                                   float* __restrict__ Yf,
                                                   float* __restrict__ statsOut,
                                                   const float* __restrict__ statsIn,
                                                   const float* __restrict__ gA,
                                                   const float* __restrict__ gB,
                                                   const float* __restrict__ bB,
                                                   int mode){
  __shared__ uint4 w4[128 * 17];
  __shared__ float ssum[128];
  __shared__ float ssq[128];
  __shared__ float sS[128];
  __shared__ float sT[128];
  const uint4* Wg = (const uint4*)W;
  for (int c = threadIdx.x; c < 2048; c += 512){
    w4[(c >> 4) * 17 + (c & 15)] = Wg[c];
  }
  if (statsIn) bn_params_tid(statsIn, gA, gB, bB, mode, sS, sT);
  if (threadIdx.x < 128){ ssum[threadIdx.x] = 0.f; ssq[threadIdx.x] = 0.f; }
  __syncthreads();

  int wave = threadIdx.x >> 6;
  int lane = threadIdx.x & 63;
  int m = lane & 15, q = lane >> 4;
  int tile = blockIdx.x * 8 + wave;
  bool tv = tile < NTILES;
  const uint4* A4 = (const uint4*)A;

  f32x4 acc[8];
#pragma unroll
  for (int i = 0; i < 8; ++i) acc[i] = (f32x4)0.f;

#pragma unroll
  for (int kt = 0; kt < 4; ++kt){
    short8 af = (short8)0;
    if (tv){
      uint4 t = A4[(tile * 16 + m) * 16 + kt * 4 + q];
      if (statsIn){
        int kc = kt * 32 + q * 8;
        uint4 pk;
        pk.x = (uint)f2bf(fmaxf(bflo(t.x)*sS[kc+0]+sT[kc+0],0.f))
             | ((uint)f2bf(fmaxf(bfhi(t.x)*sS[kc+1]+sT[kc+1],0.f)) << 16);
        pk.y = (uint)f2bf(fmaxf(bflo(t.y)*sS[kc+2]+sT[kc+2],0.f))
             | ((uint)f2bf(fmaxf(bfhi(t.y)*sS[kc+3]+sT[kc+3],0.f)) << 16);
        pk.z = (uint)f2bf(fmaxf(bflo(t.z)*sS[kc+4]+sT[kc+4],0.f))
             | ((uint)f2bf(fmaxf(bfhi(t.z)*sS[kc+5]+sT[kc+5],0.f)) << 16);
        pk.w = (uint)f2bf(fmaxf(bflo(t.w)*sS[kc+6]+sT[kc+6],0.f))
             | ((uint)f2bf(fmaxf(bfhi(t.w)*sS[kc+7]+sT[kc+7],0.f)) << 16);
        t = pk;
      }
      af = *(short8*)&t;
    }
#pragma unroll
    for (int to = 0; to < 8; ++to){
      uint4 bw = w4[(to * 16 + m) * 17 + kt * 4 + q];
      acc[to] = __builtin_amdgcn_mfma_f32_16x16x32_bf16(af, *(short8*)&bw, acc[to], 0, 0, 0);
    }
  }

  bool dost = (statsOut != nullptr);
#pragma unroll
  for (int to = 0; to < 8; ++to){
    int col = to * 16 + m;
    float bc = bias[col];
    float ls = 0.f, lq = 0.f;
    if (tv){
#pragma unroll
      for (int r = 0; r < 4; ++r){
        float v = acc[to][r] + bc;
        int row = tile * 16 + q * 4 + r;
        if (Yb) Yb[row * 128 + col] = __builtin_bit_cast(ushort, f2bf(v));
        else    Yf[row * 128 + col] = v;
        ls += v; lq += v * v;
      }
    }
    if (dost){
      ls += __shfl_xor(ls, 16); lq += __shfl_xor(lq, 16);
      ls += __shfl_xor(ls, 32); lq += __shfl_xor(lq, 32);
      if (tv && q == 0){ atomicAdd(&ssum[col], ls); atomicAdd(&ssq[col], lq); }
    }
  }
  if (dost){
    __syncthreads();
    if (threadIdx.x < 128){
      atomicAdd(&statsOut[threadIdx.x], ssum[threadIdx.x]);
      atomicAdd(&statsOut[128 + threadIdx.x], ssq[threadIdx.x]);
    }
  }
}

extern "C" void kernel_launch(void* const* d_in, const int* in_sizes, int n_in,
                              void* d_out, int out_size, void* d_ws, size_t ws_size,
                              hipStream_t stream) {
  const float* x     = (const float*)d_in[0];
  const int*   ei    = (const int*)d_in[1];
  const float* fc1_w = (const float*)d_in[2];
  const float* fc1_b = (const float*)d_in[3];
  const float* bn1_g = (const float*)d_in[4];
  const float* bn1_b = (const float*)d_in[5];
  const float* fc2_w = (const float*)d_in[6];
  const float* fc2_b = (const float*)d_in[7];
  const float* bn2_g = (const float*)d_in[8];
  const float* bn3_g = (const float*)d_in[10];
  const float* bn3_b = (const float*)d_in[11];
  const float* fc_w  = (const float*)d_in[12];
  const float* fc_b  = (const float*)d_in[13];

  int E = in_sizes[1] / 2;
  const int* srcp = ei;
  const int* dstp = ei + E;

  char* ws = (char*)d_ws;
  int*    off    = (int*)(ws + 0);           // (N+1) ints
  int*    cnt    = (int*)(ws + 200064);      // N ints
  int*    pos    = (int*)(ws + 400128);      // E ints
  int*    csrc   = (int*)(ws + 3600128);     // E ints (aliased as `incl` pre-fill2)
  ushort* wb     = (ushort*)(ws + 6800128);  // 147456 bf16
  float*  stats  = (float*)(ws + 7095040);   // 8 slices x 256 floats
  int*    sscr   = (int*)(ws + 7103232);     // scan bsum/base
  ushort* xb     = (ushort*)(ws + 7104256);  // N*128 bf16
  ushort* hb     = (ushort*)(ws + 19904256); // N*128 bf16
  ushort* y1b    = (ushort*)(ws + 32704256); // N*128 bf16
  ushort* y2b    = (ushort*)(ws + 45504256); // N*128 bf16

  int* incl = csrc;
  int* bsum = sscr;
  int* base = sscr + 64;

  hipMemsetAsync(cnt, 0, 200064, stream);
  hipMemsetAsync(stats, 0, 8192, stream);

  cast_f32_bf16x4<<<2048, 256, 0, stream>>>(x, xb, NN * HD / 4);
  cast_weights<<<144, 256, 0, stream>>>(fc1_w, fc2_w, fc_w, wb);

  const int EB4 = (E / 4 + 255) / 256 + 1;
  const int SB = (NN + 1023) / 1024;
  fill1_kernel<<<EB4, 256, 0, stream>>>(dstp, cnt, pos, E);
  scan1_kernel<<<SB, 1024, 0, stream>>>(cnt, incl, bsum, NN);
  scan2_kernel<<<1, 64, 0, stream>>>(bsum, base, off, SB, NN);
  scan3_kernel<<<SB, 1024, 0, stream>>>(cnt, incl, base, off, NN);
  fill2_kernel<<<EB4, 256, 0, stream>>>(srcp, dstp, off, pos, csrc, E);

  const int gb = (NTILES + 7) / 8;  // 391 blocks x 8 waves

  for (int i = 0; i < NL; ++i){
    if (i == 0){
      agg_kernel<<<NN / 4, 256, 0, stream>>>(xb, off, csrc, hb);
    } else {
      // gather prev y2, apply composed bn3(bn2(.))+relu of layer i-1 on the fly
      agg_bn_kernel<<<NN / 4, 256, 0, stream>>>(y2b, off, csrc,
                                                stats + (i - 1) * 512 + 256,
                                                bn2_g + (i - 1) * 128,
                                                bn3_g + (i - 1) * 128,
                                                bn3_b + (i - 1) * 128, hb);
    }
    // fc1: hb -> y1b (bf16), stats1
    gemm_kernel<<<gb, 512, 0, stream>>>(hb, wb + i * 16384, fc1_b + i * 128,
                                        y1b, nullptr, stats + i * 512,
                                        nullptr, nullptr, nullptr, nullptr, 0);
    // fc2: relu(bn1(y1b)) -> y2b (bf16), stats2; bn1 params inline from stats1
    gemm_kernel<<<gb, 512, 0, stream>>>(y1b, wb + 65536 + i * 16384, fc2_b + i * 128,
                                        y2b, nullptr, stats + i * 512 + 256,
                                        stats + i * 512, bn1_g + i * 128,
                                        bn1_b + i * 128, nullptr, 0);
  }

  // classifier: relu(bn3(bn2(y2b)))@fc_w^T + fc_b -> f32 out; bn23 params inline
  gemm_kernel<<<gb, 512, 0, stream>>>(y2b, wb + 131072, fc_b,
                                      nullptr, (float*)d_out, nullptr,
                                      stats + 3 * 512 + 256, bn2_g + 384,
                                      bn3_g + 384, bn3_b + 384, 1);
}